// Round 1
// baseline (899.009 us; speedup 1.0000x reference)
//
#include <hip/hip_runtime.h>
#include <stdint.h>

#define B_ 2
#define S_ 2048
#define D_ 4096
#define H_ 32
#define KVH_ 8
#define HD_ 128
#define GRP_ (H_/KVH_)
#define NQKV 6144
#define MULT_ 0.08838834764831845f
#define MAXV_ 30.0f

typedef __attribute__((ext_vector_type(8))) short s16x8;
typedef __attribute__((ext_vector_type(4))) float fx4;

__device__ __forceinline__ unsigned short f2bf(float f) {
  unsigned int u = __float_as_uint(f);
  u += 0x7fffu + ((u >> 16) & 1u);
  return (unsigned short)(u >> 16);
}
__device__ __forceinline__ float bf2f(unsigned short h) {
  return __uint_as_float(((unsigned int)h) << 16);
}

__device__ __forceinline__ void gld_lds16(const void* g, void* l) {
  __builtin_amdgcn_global_load_lds(
      (const __attribute__((address_space(1))) unsigned int*)g,
      (__attribute__((address_space(3))) unsigned int*)l, 16, 0, 0);
}

// ---------------- prep kernels ----------------

__global__ void k_f2bf(const float* __restrict__ src, unsigned short* __restrict__ dst, int n4) {
  int i = blockIdx.x * blockDim.x + threadIdx.x;
  int stride = gridDim.x * blockDim.x;
  for (; i < n4; i += stride) {
    float4 v = ((const float4*)src)[i];
    ushort4 o;
    o.x = f2bf(v.x); o.y = f2bf(v.y); o.z = f2bf(v.z); o.w = f2bf(v.w);
    ((ushort4*)dst)[i] = o;
  }
}

// dst[n*4096 + k] = (bf16) src[k*ncols + n]
__global__ void k_transpose_w(const float* __restrict__ src, int ncols,
                              unsigned short* __restrict__ dst) {
  __shared__ float tile[32][33];
  int k0 = blockIdx.x * 32;
  int n0 = blockIdx.y * 32;
  int tx = threadIdx.x, ty = threadIdx.y;
  for (int i = 0; i < 32; i += 8)
    tile[ty + i][tx] = src[(size_t)(k0 + ty + i) * ncols + n0 + tx];
  __syncthreads();
  for (int i = 0; i < 32; i += 8)
    dst[(size_t)(n0 + ty + i) * 4096 + k0 + tx] = f2bf(tile[tx][ty + i]);
}

// vt[(bk*128 + d)*S + s] = qkv[(b*S+s)*NQKV + 5120 + kvh*128 + d]
__global__ void k_transpose_v(const unsigned short* __restrict__ qkv,
                              unsigned short* __restrict__ vt) {
  __shared__ unsigned short tile[32][33];
  int s0 = blockIdx.x * 32;
  int d0 = blockIdx.y * 32;
  int bk = blockIdx.z;
  int b = bk / KVH_, kvh = bk % KVH_;
  int tx = threadIdx.x, ty = threadIdx.y;
  for (int i = 0; i < 32; i += 8)
    tile[ty + i][tx] = qkv[(size_t)(b*S_ + s0 + ty + i)*NQKV + 5120 + kvh*HD_ + d0 + tx];
  __syncthreads();
  for (int i = 0; i < 32; i += 8)
    vt[((size_t)bk*HD_ + d0 + ty + i)*S_ + s0 + tx] = tile[tx][ty + i];
}

// RoPE for Q and K; one block per (b,s)
__global__ void k_rope(const unsigned short* __restrict__ qkv,
                       unsigned short* __restrict__ Q, unsigned short* __restrict__ K) {
  int bs = blockIdx.x;
  int b = bs >> 11;
  int s = bs & (S_ - 1);
  __shared__ float cs[64], sn[64];
  int t = threadIdx.x;
  if (t < 64) {
    float inv = __expf(-(float)t * 0.14391156831212787f); // ln(10000)/64
    float fr = (float)s * inv;
    cs[t] = cosf(fr); sn[t] = sinf(fr);
  }
  __syncthreads();
  const unsigned short* row = qkv + (size_t)bs * NQKV;
  for (int i = t; i < H_*HD_; i += 256) {
    int h = i >> 7, d = i & 127;
    float x = bf2f(row[i]);
    float x2, c, si;
    if (d < 64) { x2 = -bf2f(row[h*128 + d + 64]); c = cs[d];    si = sn[d]; }
    else        { x2 =  bf2f(row[h*128 + d - 64]); c = cs[d-64]; si = sn[d-64]; }
    Q[((size_t)(b*H_ + h)*S_ + s)*HD_ + d] = f2bf(x*c + x2*si);
  }
  for (int i = t; i < KVH_*HD_; i += 256) {
    int h = i >> 7, d = i & 127;
    float x = bf2f(row[4096 + i]);
    float x2, c, si;
    if (d < 64) { x2 = -bf2f(row[4096 + h*128 + d + 64]); c = cs[d];    si = sn[d]; }
    else        { x2 =  bf2f(row[4096 + h*128 + d - 64]); c = cs[d-64]; si = sn[d-64]; }
    K[((size_t)(b*KVH_ + h)*S_ + s)*HD_ + d] = f2bf(x*c + x2*si);
  }
}

// ---------------- GEMM: C[M][N] = A[M][K] * Bt[N][K]^T ----------------
// 128x128 tile, BK=32, 4 waves (2x2 of 64x64), XOR-swizzled LDS (swizzle applied
// on the global source so global_load_lds linear dest works; reads apply same XOR).

template<int OUTF32>
__global__ __launch_bounds__(256)
void k_gemm_bt(const unsigned short* __restrict__ A, const unsigned short* __restrict__ Bt,
               void* __restrict__ C, int M, int N, int K) {
  __shared__ unsigned short a_lds[128*32];
  __shared__ unsigned short b_lds[128*32];
  int bm = blockIdx.x, bn = blockIdx.y;
  int tid = threadIdx.x;
  int lane = tid & 63, wv = tid >> 6;
  int wr = wv & 1, wc = wv >> 1;
  int l15 = lane & 15, l4 = lane >> 4;
  fx4 acc[4][4] = {};
  for (int k0 = 0; k0 < K; k0 += 32) {
    for (int it = 0; it < 2; ++it) {
      int c = it*256 + wv*64 + lane;
      int r = c >> 2;
      int kk = ((c & 3) ^ (r & 3)) * 8;   // source pre-swizzle
      gld_lds16(A  + (size_t)(bm*128 + r)*K + k0 + kk, &a_lds[it*2048 + wv*512]);
      gld_lds16(Bt + (size_t)(bn*128 + r)*K + k0 + kk, &b_lds[it*2048 + wv*512]);
    }
    __syncthreads();
    s16x8 af[4], bg[4];
    for (int i = 0; i < 4; ++i) {
      int ra = wr*64 + i*16 + l15;
      int rb = wc*64 + i*16 + l15;
      af[i] = *(const s16x8*)&a_lds[ra*32 + ((l4 ^ (l15 & 3)) * 8)];
      bg[i] = *(const s16x8*)&b_lds[rb*32 + ((l4 ^ (l15 & 3)) * 8)];
    }
    for (int i = 0; i < 4; ++i)
      for (int j = 0; j < 4; ++j)
        acc[i][j] = __builtin_amdgcn_mfma_f32_16x16x32_bf16(af[i], bg[j], acc[i][j], 0, 0, 0);
    __syncthreads();
  }
  for (int i = 0; i < 4; ++i)
    for (int j = 0; j < 4; ++j)
      for (int r = 0; r < 4; ++r) {
        int m = bm*128 + wr*64 + i*16 + l4*4 + r;
        int n = bn*128 + wc*64 + j*16 + l15;
        float v = acc[i][j][r];
        if (OUTF32) ((float*)C)[(size_t)m*N + n] = v;
        else ((unsigned short*)C)[(size_t)m*N + n] = f2bf(v);
      }
}

// ---------------- attention ----------------
// grid (S/64, B*H); 4 waves, each owns 16 q rows; KV tiles of 32 keys.
// Soft cap bounds scores by 30 -> fixed-max softmax exp(s-30), running sum only.

__global__ __launch_bounds__(256)
void k_attn(const unsigned short* __restrict__ Q, const unsigned short* __restrict__ K,
            const unsigned short* __restrict__ Vt, unsigned short* __restrict__ Aout) {
  __shared__ unsigned short k_lds[32*128];   // [key][d] (d-blocks swizzled)
  __shared__ unsigned short v_lds[128*32];   // [d][key] (k-blocks swizzled)
  __shared__ unsigned short p_lds[4*16*32];  // per-wave P tile
  int q0 = blockIdx.x * 64;
  int bh = blockIdx.y;
  int b = bh / H_, h = bh % H_;
  int kvh = h / GRP_;
  int tid = threadIdx.x, lane = tid & 63, wv = tid >> 6;
  int l15 = lane & 15, l4 = lane >> 4;
  const unsigned short* Qb = Q + (size_t)bh * S_ * HD_;
  const unsigned short* Kb = K + (size_t)(b*KVH_ + kvh) * S_ * HD_;
  const unsigned short* Vb = Vt + (size_t)(b*KVH_ + kvh) * HD_ * S_;
  int qrow = q0 + wv*16;
  s16x8 aq[4];
  for (int kb = 0; kb < 4; ++kb)
    aq[kb] = *(const s16x8*)&Qb[(size_t)(qrow + l15)*HD_ + kb*32 + l4*8];
  fx4 oacc[8] = {};
  float sump[4] = {0.f, 0.f, 0.f, 0.f};
  unsigned short* p_w = p_lds + wv*512;
  int ntiles = q0/32 + 2;
  for (int t = 0; t < ntiles; ++t) {
    int kbase = t*32;
    for (int it = 0; it < 2; ++it) {
      int c = it*256 + wv*64 + lane;
      int kr = c >> 4;                              // K tile: [32 keys][16 blocks]
      int kd = ((c & 15) ^ (kr & 7)) * 8;
      gld_lds16(&Kb[(size_t)(kbase + kr)*HD_ + kd], &k_lds[it*2048 + wv*512]);
      int vd = c >> 2;                              // V tile: [128 d][4 blocks]
      int vk = ((c & 3) ^ (vd & 3)) * 8;
      gld_lds16(&Vb[(size_t)vd*S_ + kbase + vk], &v_lds[it*2048 + wv*512]);
    }
    __syncthreads();
    for (int nb = 0; nb < 2; ++nb) {
      fx4 s = {0.f, 0.f, 0.f, 0.f};
      for (int kb = 0; kb < 4; ++kb) {
        int lb = (kb*4 + l4) ^ (l15 & 7);
        s16x8 bk = *(const s16x8*)&k_lds[(nb*16 + l15)*128 + lb*8];
        s = __builtin_amdgcn_mfma_f32_16x16x32_bf16(aq[kb], bk, s, 0, 0, 0);
      }
      int kcol = kbase + nb*16 + l15;
      for (int r = 0; r < 4; ++r) {
        int qr = qrow + l4*4 + r;
        float sc = s[r] * MULT_;
        // stable 30*tanh(sc/30)
        float x = sc * (1.0f/MAXV_);
        float ax = fabsf(x);
        float e2 = __expf(-2.0f * ax);
        float th = (1.0f - e2) / (1.0f + e2);
        sc = MAXV_ * (x < 0.0f ? -th : th);
        float p = (kcol <= qr) ? __expf(sc - MAXV_) : 0.0f;
        unsigned short pb = f2bf(p);
        sump[r] += bf2f(pb);
        p_w[(l4*4 + r)*32 + nb*16 + l15] = pb;
      }
    }
    s16x8 ap = *(const s16x8*)&p_w[l15*32 + l4*8];
    for (int db = 0; db < 8; ++db) {
      int d = db*16 + l15;
      s16x8 bv = *(const s16x8*)&v_lds[d*32 + ((l4 ^ (d & 3)) * 8)];
      oacc[db] = __builtin_amdgcn_mfma_f32_16x16x32_bf16(ap, bv, oacc[db], 0, 0, 0);
    }
    __syncthreads();
  }
  for (int off = 1; off < 16; off <<= 1)
    for (int r = 0; r < 4; ++r)
      sump[r] += __shfl_xor(sump[r], off);
  for (int db = 0; db < 8; ++db)
    for (int r = 0; r < 4; ++r) {
      int qr = qrow + l4*4 + r;
      int d = db*16 + l15;
      Aout[(size_t)(b*S_ + qr)*4096 + h*HD_ + d] = f2bf(oacc[db][r] / sump[r]);
    }
}

// ---------------- launch ----------------

extern "C" void kernel_launch(void* const* d_in, const int* in_sizes, int n_in,
                              void* d_out, int out_size, void* d_ws, size_t ws_size,
                              hipStream_t stream) {
  (void)in_sizes; (void)n_in; (void)out_size; (void)ws_size;
  const float* hidden = (const float*)d_in[0];
  const float* q_w = (const float*)d_in[3];
  const float* k_w = (const float*)d_in[4];
  const float* v_w = (const float*)d_in[5];
  const float* o_w = (const float*)d_in[6];
  char* ws = (char*)d_ws;
  unsigned short* hidden_bf = (unsigned short*)(ws + 0);           // 32 MiB
  unsigned short* qkv_wt    = (unsigned short*)(ws + 33554432);    // 48 MiB
  unsigned short* o_wt      = (unsigned short*)(ws + 83886080);    // 32 MiB
  unsigned short* qkv       = (unsigned short*)(ws + 117440512);   // 48 MiB
  unsigned short* Qb        = (unsigned short*)(ws + 167772160);   // 32 MiB
  unsigned short* Kb        = (unsigned short*)(ws + 201326592);   // 8 MiB
  unsigned short* Vt        = (unsigned short*)(ws + 209715200);   // 8 MiB
  unsigned short* attn_out  = (unsigned short*)(ws + 218103808);   // 32 MiB

  dim3 tb(32, 8);
  k_f2bf<<<2048, 256, 0, stream>>>(hidden, hidden_bf, (B_*S_*D_)/4);
  k_transpose_w<<<dim3(128, 128), tb, 0, stream>>>(q_w, 4096, qkv_wt);
  k_transpose_w<<<dim3(128, 32),  tb, 0, stream>>>(k_w, 1024, qkv_wt + (size_t)4096*4096);
  k_transpose_w<<<dim3(128, 32),  tb, 0, stream>>>(v_w, 1024, qkv_wt + (size_t)5120*4096);
  k_transpose_w<<<dim3(128, 128), tb, 0, stream>>>(o_w, 4096, o_wt);
  k_gemm_bt<0><<<dim3(32, 48), 256, 0, stream>>>(hidden_bf, qkv_wt, qkv, B_*S_, NQKV, D_);
  k_rope<<<B_*S_, 256, 0, stream>>>(qkv, Qb, Kb);
  k_transpose_v<<<dim3(S_/32, HD_/32, B_*KVH_), tb, 0, stream>>>(qkv, Vt);
  k_attn<<<dim3(S_/64, B_*H_), 256, 0, stream>>>(Qb, Kb, Vt, attn_out);
  k_gemm_bt<1><<<dim3(32, 32), 256, 0, stream>>>(attn_out, o_wt, d_out, B_*S_, D_, D_);
}

// Round 2
// 763.402 us; speedup vs baseline: 1.1776x; 1.1776x over previous
//
#include <hip/hip_runtime.h>
#include <stdint.h>

#define B_ 2
#define S_ 2048
#define D_ 4096
#define H_ 32
#define KVH_ 8
#define HD_ 128
#define GRP_ (H_/KVH_)
#define NQKV 6144
#define MULT_ 0.08838834764831845f
#define MAXV_ 30.0f

typedef __attribute__((ext_vector_type(8))) short s16x8;
typedef __attribute__((ext_vector_type(4))) float fx4;

__device__ __forceinline__ unsigned short f2bf(float f) {
  unsigned int u = __float_as_uint(f);
  u += 0x7fffu + ((u >> 16) & 1u);
  return (unsigned short)(u >> 16);
}
__device__ __forceinline__ float bf2f(unsigned short h) {
  return __uint_as_float(((unsigned int)h) << 16);
}
__device__ __forceinline__ uint32_t pk2(float lo, float hi) {
  return ((uint32_t)f2bf(hi) << 16) | (uint32_t)f2bf(lo);
}

__device__ __forceinline__ void gld_lds16(const void* g, void* l) {
  __builtin_amdgcn_global_load_lds(
      (const __attribute__((address_space(1))) unsigned int*)g,
      (__attribute__((address_space(3))) unsigned int*)l, 16, 0, 0);
}

// ---------------- prep kernels ----------------

__global__ void k_f2bf(const float* __restrict__ src, unsigned short* __restrict__ dst, int n4) {
  int i = blockIdx.x * blockDim.x + threadIdx.x;
  int stride = gridDim.x * blockDim.x;
  for (; i < n4; i += stride) {
    float4 v = ((const float4*)src)[i];
    ushort4 o;
    o.x = f2bf(v.x); o.y = f2bf(v.y); o.z = f2bf(v.z); o.w = f2bf(v.w);
    ((ushort4*)dst)[i] = o;
  }
}

// dst[n*4096 + k] = (bf16) src[k*ncols + n]
__global__ void k_transpose_w(const float* __restrict__ src, int ncols,
                              unsigned short* __restrict__ dst) {
  __shared__ float tile[32][33];
  int k0 = blockIdx.x * 32;
  int n0 = blockIdx.y * 32;
  int tx = threadIdx.x, ty = threadIdx.y;
  for (int i = 0; i < 32; i += 8)
    tile[ty + i][tx] = src[(size_t)(k0 + ty + i) * ncols + n0 + tx];
  __syncthreads();
  for (int i = 0; i < 32; i += 8)
    dst[(size_t)(n0 + ty + i) * 4096 + k0 + tx] = f2bf(tile[tx][ty + i]);
}

// vt[(bk*128 + d)*S + s] = qkv[(b*S+s)*NQKV + 5120 + kvh*128 + d]
__global__ void k_transpose_v(const unsigned short* __restrict__ qkv,
                              unsigned short* __restrict__ vt) {
  __shared__ unsigned short tile[32][33];
  int s0 = blockIdx.x * 32;
  int d0 = blockIdx.y * 32;
  int bk = blockIdx.z;
  int b = bk / KVH_, kvh = bk % KVH_;
  int tx = threadIdx.x, ty = threadIdx.y;
  for (int i = 0; i < 32; i += 8)
    tile[ty + i][tx] = qkv[(size_t)(b*S_ + s0 + ty + i)*NQKV + 5120 + kvh*HD_ + d0 + tx];
  __syncthreads();
  for (int i = 0; i < 32; i += 8)
    vt[((size_t)bk*HD_ + d0 + ty + i)*S_ + s0 + tx] = tile[tx][ty + i];
}

// RoPE for Q and K; one block per (b,s)
__global__ void k_rope(const unsigned short* __restrict__ qkv,
                       unsigned short* __restrict__ Q, unsigned short* __restrict__ K) {
  int bs = blockIdx.x;
  int b = bs >> 11;
  int s = bs & (S_ - 1);
  __shared__ float cs[64], sn[64];
  int t = threadIdx.x;
  if (t < 64) {
    float inv = __expf(-(float)t * 0.14391156831212787f); // ln(10000)/64
    float fr = (float)s * inv;
    cs[t] = cosf(fr); sn[t] = sinf(fr);
  }
  __syncthreads();
  const unsigned short* row = qkv + (size_t)bs * NQKV;
  for (int i = t; i < H_*HD_; i += 256) {
    int h = i >> 7, d = i & 127;
    float x = bf2f(row[i]);
    float x2, c, si;
    if (d < 64) { x2 = -bf2f(row[h*128 + d + 64]); c = cs[d];    si = sn[d]; }
    else        { x2 =  bf2f(row[h*128 + d - 64]); c = cs[d-64]; si = sn[d-64]; }
    Q[((size_t)(b*H_ + h)*S_ + s)*HD_ + d] = f2bf(x*c + x2*si);
  }
  for (int i = t; i < KVH_*HD_; i += 256) {
    int h = i >> 7, d = i & 127;
    float x = bf2f(row[4096 + i]);
    float x2, c, si;
    if (d < 64) { x2 = -bf2f(row[4096 + h*128 + d + 64]); c = cs[d];    si = sn[d]; }
    else        { x2 =  bf2f(row[4096 + h*128 + d - 64]); c = cs[d-64]; si = sn[d-64]; }
    K[((size_t)(b*KVH_ + h)*S_ + s)*HD_ + d] = f2bf(x*c + x2*si);
  }
}

// ---------------- GEMM: C[M][N] = A[M][K] * Bt[N][K]^T ----------------

template<int OUTF32>
__global__ __launch_bounds__(256)
void k_gemm_bt(const unsigned short* __restrict__ A, const unsigned short* __restrict__ Bt,
               void* __restrict__ C, int M, int N, int K) {
  __shared__ unsigned short a_lds[128*32];
  __shared__ unsigned short b_lds[128*32];
  int bm = blockIdx.x, bn = blockIdx.y;
  int tid = threadIdx.x;
  int lane = tid & 63, wv = tid >> 6;
  int wr = wv & 1, wc = wv >> 1;
  int l15 = lane & 15, l4 = lane >> 4;
  fx4 acc[4][4] = {};
  for (int k0 = 0; k0 < K; k0 += 32) {
    for (int it = 0; it < 2; ++it) {
      int c = it*256 + wv*64 + lane;
      int r = c >> 2;
      int kk = ((c & 3) ^ (r & 3)) * 8;   // source pre-swizzle
      gld_lds16(A  + (size_t)(bm*128 + r)*K + k0 + kk, &a_lds[it*2048 + wv*512]);
      gld_lds16(Bt + (size_t)(bn*128 + r)*K + k0 + kk, &b_lds[it*2048 + wv*512]);
    }
    __syncthreads();
    s16x8 af[4], bg[4];
    for (int i = 0; i < 4; ++i) {
      int ra = wr*64 + i*16 + l15;
      int rb = wc*64 + i*16 + l15;
      af[i] = *(const s16x8*)&a_lds[ra*32 + ((l4 ^ (l15 & 3)) * 8)];
      bg[i] = *(const s16x8*)&b_lds[rb*32 + ((l4 ^ (l15 & 3)) * 8)];
    }
    for (int i = 0; i < 4; ++i)
      for (int j = 0; j < 4; ++j)
        acc[i][j] = __builtin_amdgcn_mfma_f32_16x16x32_bf16(af[i], bg[j], acc[i][j], 0, 0, 0);
    __syncthreads();
  }
  for (int i = 0; i < 4; ++i)
    for (int j = 0; j < 4; ++j)
      for (int r = 0; r < 4; ++r) {
        int m = bm*128 + wr*64 + i*16 + l4*4 + r;
        int n = bn*128 + wc*64 + j*16 + l15;
        float v = acc[i][j][r];
        if (OUTF32) ((float*)C)[(size_t)m*N + n] = v;
        else ((unsigned short*)C)[(size_t)m*N + n] = f2bf(v);
      }
}

// ---------------- attention v2 ----------------
// Swapped QK^T (mfma(K,Q)) -> lane owns one q-row's P slice; fixed-max softmax
// (softcap bounds scores by 30); in-register P redistribution via shfl_xor;
// 32 q-rows/wave; causal pairing of 128-row strips (t, 15-t) -> uniform 68 tiles.

__global__ __launch_bounds__(256)
void k_attn2(const unsigned short* __restrict__ Q, const unsigned short* __restrict__ K,
             const unsigned short* __restrict__ Vt, unsigned short* __restrict__ Aout) {
  __shared__ unsigned short k_lds[32*128];   // [key][d] (d-blocks swizzled by key&7)
  __shared__ unsigned short v_lds[128*32];   // [d][key] (k-blocks swizzled by d&3)
  const float C1 = 0.08838834764831845f * 2.0f * 1.4426950408889634f / 30.0f;
  const float C2 = 30.0f * 1.4426950408889634f;
  int tpair = blockIdx.x;           // 0..7
  int bh = blockIdx.y;
  int b = bh / H_, h = bh % H_;
  int kvh = h / GRP_;
  int tid = threadIdx.x, lane = tid & 63, wv = tid >> 6;
  int l15 = lane & 15, l4 = lane >> 4;
  const unsigned short* Qb = Q + (size_t)bh * S_ * HD_;
  const unsigned short* Kb = K + (size_t)(b*KVH_ + kvh) * S_ * HD_;
  const unsigned short* Vb = Vt + (size_t)(b*KVH_ + kvh) * HD_ * S_;

  for (int sp = 0; sp < 2; ++sp) {
    int strip = sp ? (15 - tpair) : tpair;
    int q0 = strip * 128;
    int qbase = q0 + wv * 32;
    // Q as B-fragment: col=l15 -> q row, kdim = kb*32 + l4*8 + j
    s16x8 bq[2][4];
#pragma unroll
    for (int qf = 0; qf < 2; ++qf)
#pragma unroll
      for (int kb = 0; kb < 4; ++kb)
        bq[qf][kb] = *(const s16x8*)&Qb[(size_t)(qbase + qf*16 + l15)*HD_ + kb*32 + l4*8];
    fx4 oacc[2][8] = {};
    float sump[2] = {0.f, 0.f};
    int ntiles = q0/32 + 4;
    for (int t = 0; t < ntiles; ++t) {
      int kbase = t*32;
      for (int it = 0; it < 2; ++it) {
        int c = it*256 + tid;
        int kr = c >> 4;                              // K tile: [32 keys][16 d-blocks]
        int kd = ((c & 15) ^ (kr & 7)) * 8;
        gld_lds16(&Kb[(size_t)(kbase + kr)*HD_ + kd], &k_lds[it*2048 + wv*512]);
        int vd = c >> 2;                              // V tile: [128 d][4 k-blocks]
        int vk = ((c & 3) ^ (vd & 3)) * 8;
        gld_lds16(&Vb[(size_t)vd*S_ + kbase + vk], &v_lds[it*2048 + wv*512]);
      }
      __syncthreads();
      if (kbase <= qbase + 31) {   // wave-uniform: any unmasked key in tile
        // S^T = K x Q : C col=l15 -> q, row=l4*4+r -> key
        fx4 sst[2][2] = {};
#pragma unroll
        for (int nb = 0; nb < 2; ++nb)
#pragma unroll
          for (int kb = 0; kb < 4; ++kb) {
            s16x8 kf = *(const s16x8*)&k_lds[(nb*16 + l15)*128 + (((kb*4 + l4) ^ (l15 & 7)) * 8)];
            sst[nb][0] = __builtin_amdgcn_mfma_f32_16x16x32_bf16(kf, bq[0][kb], sst[nb][0], 0, 0, 0);
            sst[nb][1] = __builtin_amdgcn_mfma_f32_16x16x32_bf16(kf, bq[1][kb], sst[nb][1], 0, 0, 0);
          }
        s16x8 pf[2];
#pragma unroll
        for (int qf = 0; qf < 2; ++qf) {
          int qr = qbase + qf*16 + l15;
          uint32_t w[4];
          float psum = 0.f;
#pragma unroll
          for (int nb = 0; nb < 2; ++nb) {
            float pv[4];
#pragma unroll
            for (int r = 0; r < 4; ++r) {
              int kk = kbase + nb*16 + l4*4 + r;
              float sraw = sst[nb][qf][r];
              // p = exp(30*tanh(sraw*MULT/30) - 30), fixed-max softmax numerator
              float e2 = __builtin_amdgcn_exp2f(-fabsf(sraw) * C1);
              float th = (1.f - e2) * __builtin_amdgcn_rcpf(1.f + e2);
              float th_s = __uint_as_float(__float_as_uint(th) |
                                           (__float_as_uint(sraw) & 0x80000000u));
              float p = __builtin_amdgcn_exp2f(th_s * C2 - C2);
              p = (kk <= qr) ? p : 0.f;
              psum += p;
              pv[r] = p;
            }
            w[nb*2]   = pk2(pv[0], pv[1]);
            w[nb*2+1] = pk2(pv[2], pv[3]);
          }
          sump[qf] += psum;
          // redistribute: lane g=l4 needs k in [8g, 8g+8) as B-fragment words
          uint32_t a0x = __shfl_xor((int)w[0], 16), a1x = __shfl_xor((int)w[1], 16);
          uint32_t b0x = __shfl_xor((int)w[2], 16), b1x = __shfl_xor((int)w[3], 16);
          bool up = (l4 & 1);
          uint32_t VA0 = up ? a0x : w[0], VA1 = up ? a1x : w[1];
          uint32_t VA2 = up ? w[0] : a0x, VA3 = up ? w[1] : a1x;
          uint32_t VB0 = up ? b0x : w[2], VB1 = up ? b1x : w[3];
          uint32_t VB2 = up ? w[2] : b0x, VB3 = up ? w[3] : b1x;
          bool lowh = (l4 < 2);
          uint32_t X0 = lowh ? VB0 : VA0, X1 = lowh ? VB1 : VA1;
          uint32_t X2 = lowh ? VB2 : VA2, X3 = lowh ? VB3 : VA3;
          uint32_t Y0 = __shfl_xor((int)X0, 32), Y1 = __shfl_xor((int)X1, 32);
          uint32_t Y2 = __shfl_xor((int)X2, 32), Y3 = __shfl_xor((int)X3, 32);
          union { uint32_t u[4]; s16x8 v; } tw;
          tw.u[0] = (l4 == 0) ? VA0 : (l4 == 3) ? VB0 : Y0;
          tw.u[1] = (l4 == 0) ? VA1 : (l4 == 3) ? VB1 : Y1;
          tw.u[2] = (l4 == 0) ? VA2 : (l4 == 3) ? VB2 : Y2;
          tw.u[3] = (l4 == 0) ? VA3 : (l4 == 3) ? VB3 : Y3;
          pf[qf] = tw.v;
        }
        // O^T = V^T x P^T : C col=l15 -> q, row=l4*4+r -> d-local
#pragma unroll
        for (int db = 0; db < 8; ++db) {
          int d = db*16 + l15;
          s16x8 vf = *(const s16x8*)&v_lds[d*32 + ((l4 ^ (d & 3)) * 8)];
          oacc[0][db] = __builtin_amdgcn_mfma_f32_16x16x32_bf16(vf, pf[0], oacc[0][db], 0, 0, 0);
          oacc[1][db] = __builtin_amdgcn_mfma_f32_16x16x32_bf16(vf, pf[1], oacc[1][db], 0, 0, 0);
        }
      }
      __syncthreads();
    }
    // epilogue: reduce sump over l4 groups, normalize, packed store
#pragma unroll
    for (int qf = 0; qf < 2; ++qf) {
      float s = sump[qf];
      s += __shfl_xor(s, 16);
      s += __shfl_xor(s, 32);
      float rn = __builtin_amdgcn_rcpf(s);
      int q = qbase + qf*16 + l15;
#pragma unroll
      for (int db = 0; db < 8; ++db) {
        ushort4 o;
        o.x = f2bf(oacc[qf][db][0] * rn);
        o.y = f2bf(oacc[qf][db][1] * rn);
        o.z = f2bf(oacc[qf][db][2] * rn);
        o.w = f2bf(oacc[qf][db][3] * rn);
        *(ushort4*)&Aout[(size_t)(b*S_ + q)*4096 + h*HD_ + db*16 + l4*4] = o;
      }
    }
  }
}

// ---------------- launch ----------------

extern "C" void kernel_launch(void* const* d_in, const int* in_sizes, int n_in,
                              void* d_out, int out_size, void* d_ws, size_t ws_size,
                              hipStream_t stream) {
  (void)in_sizes; (void)n_in; (void)out_size; (void)ws_size;
  const float* hidden = (const float*)d_in[0];
  const float* q_w = (const float*)d_in[3];
  const float* k_w = (const float*)d_in[4];
  const float* v_w = (const float*)d_in[5];
  const float* o_w = (const float*)d_in[6];
  char* ws = (char*)d_ws;
  unsigned short* hidden_bf = (unsigned short*)(ws + 0);           // 32 MiB
  unsigned short* qkv_wt    = (unsigned short*)(ws + 33554432);    // 48 MiB
  unsigned short* o_wt      = (unsigned short*)(ws + 83886080);    // 32 MiB
  unsigned short* qkv       = (unsigned short*)(ws + 117440512);   // 48 MiB
  unsigned short* Qb        = (unsigned short*)(ws + 167772160);   // 32 MiB
  unsigned short* Kb        = (unsigned short*)(ws + 201326592);   // 8 MiB
  unsigned short* Vt        = (unsigned short*)(ws + 209715200);   // 8 MiB
  unsigned short* attn_out  = (unsigned short*)(ws + 218103808);   // 32 MiB

  dim3 tb(32, 8);
  k_f2bf<<<2048, 256, 0, stream>>>(hidden, hidden_bf, (B_*S_*D_)/4);
  k_transpose_w<<<dim3(128, 128), tb, 0, stream>>>(q_w, 4096, qkv_wt);
  k_transpose_w<<<dim3(128, 32),  tb, 0, stream>>>(k_w, 1024, qkv_wt + (size_t)4096*4096);
  k_transpose_w<<<dim3(128, 32),  tb, 0, stream>>>(v_w, 1024, qkv_wt + (size_t)5120*4096);
  k_transpose_w<<<dim3(128, 128), tb, 0, stream>>>(o_w, 4096, o_wt);
  k_gemm_bt<0><<<dim3(32, 48), 256, 0, stream>>>(hidden_bf, qkv_wt, qkv, B_*S_, NQKV, D_);
  k_rope<<<B_*S_, 256, 0, stream>>>(qkv, Qb, Kb);
  k_transpose_v<<<dim3(S_/32, HD_/32, B_*KVH_), tb, 0, stream>>>(qkv, Vt);
  k_attn2<<<dim3(8, B_*H_), 256, 0, stream>>>(Qb, Kb, Vt, attn_out);
  k_gemm_bt<1><<<dim3(32, 32), 256, 0, stream>>>(attn_out, o_wt, d_out, B_*S_, D_, D_);
}

// Round 3
// 595.327 us; speedup vs baseline: 1.5101x; 1.2823x over previous
//
#include <hip/hip_runtime.h>
#include <stdint.h>

#define B_ 2
#define S_ 2048
#define D_ 4096
#define H_ 32
#define KVH_ 8
#define HD_ 128
#define GRP_ (H_/KVH_)
#define NQKV 6144
#define MULT_ 0.08838834764831845f
#define MAXV_ 30.0f

typedef __attribute__((ext_vector_type(8))) short s16x8;
typedef __attribute__((ext_vector_type(4))) float fx4;

__device__ __forceinline__ unsigned short f2bf(float f) {
  unsigned int u = __float_as_uint(f);
  u += 0x7fffu + ((u >> 16) & 1u);
  return (unsigned short)(u >> 16);
}
__device__ __forceinline__ float bf2f(unsigned short h) {
  return __uint_as_float(((unsigned int)h) << 16);
}
__device__ __forceinline__ uint32_t pk2(float lo, float hi) {
  return ((uint32_t)f2bf(hi) << 16) | (uint32_t)f2bf(lo);
}

__device__ __forceinline__ void gld_lds16(const void* g, void* l) {
  __builtin_amdgcn_global_load_lds(
      (const __attribute__((address_space(1))) unsigned int*)g,
      (__attribute__((address_space(3))) unsigned int*)l, 16, 0, 0);
}

// ---------------- prep kernels ----------------

__global__ void k_f2bf(const float* __restrict__ src, unsigned short* __restrict__ dst, int n4) {
  int i = blockIdx.x * blockDim.x + threadIdx.x;
  int stride = gridDim.x * blockDim.x;
  for (; i < n4; i += stride) {
    float4 v = ((const float4*)src)[i];
    ushort4 o;
    o.x = f2bf(v.x); o.y = f2bf(v.y); o.z = f2bf(v.z); o.w = f2bf(v.w);
    ((ushort4*)dst)[i] = o;
  }
}

__global__ void k_transpose_w(const float* __restrict__ src, int ncols,
                              unsigned short* __restrict__ dst) {
  __shared__ float tile[32][33];
  int k0 = blockIdx.x * 32;
  int n0 = blockIdx.y * 32;
  int tx = threadIdx.x, ty = threadIdx.y;
  for (int i = 0; i < 32; i += 8)
    tile[ty + i][tx] = src[(size_t)(k0 + ty + i) * ncols + n0 + tx];
  __syncthreads();
  for (int i = 0; i < 32; i += 8)
    dst[(size_t)(n0 + ty + i) * 4096 + k0 + tx] = f2bf(tile[tx][ty + i]);
}

__global__ void k_transpose_v(const unsigned short* __restrict__ qkv,
                              unsigned short* __restrict__ vt) {
  __shared__ unsigned short tile[32][33];
  int s0 = blockIdx.x * 32;
  int d0 = blockIdx.y * 32;
  int bk = blockIdx.z;
  int b = bk / KVH_, kvh = bk % KVH_;
  int tx = threadIdx.x, ty = threadIdx.y;
  for (int i = 0; i < 32; i += 8)
    tile[ty + i][tx] = qkv[(size_t)(b*S_ + s0 + ty + i)*NQKV + 5120 + kvh*HD_ + d0 + tx];
  __syncthreads();
  for (int i = 0; i < 32; i += 8)
    vt[((size_t)bk*HD_ + d0 + ty + i)*S_ + s0 + tx] = tile[tx][ty + i];
}

__global__ void k_rope(const unsigned short* __restrict__ qkv,
                       unsigned short* __restrict__ Q, unsigned short* __restrict__ K) {
  int bs = blockIdx.x;
  int b = bs >> 11;
  int s = bs & (S_ - 1);
  __shared__ float cs[64], sn[64];
  int t = threadIdx.x;
  if (t < 64) {
    float inv = __expf(-(float)t * 0.14391156831212787f);
    float fr = (float)s * inv;
    cs[t] = cosf(fr); sn[t] = sinf(fr);
  }
  __syncthreads();
  const unsigned short* row = qkv + (size_t)bs * NQKV;
  for (int i = t; i < H_*HD_; i += 256) {
    int h = i >> 7, d = i & 127;
    float x = bf2f(row[i]);
    float x2, c, si;
    if (d < 64) { x2 = -bf2f(row[h*128 + d + 64]); c = cs[d];    si = sn[d]; }
    else        { x2 =  bf2f(row[h*128 + d - 64]); c = cs[d-64]; si = sn[d-64]; }
    Q[((size_t)(b*H_ + h)*S_ + s)*HD_ + d] = f2bf(x*c + x2*si);
  }
  for (int i = t; i < KVH_*HD_; i += 256) {
    int h = i >> 7, d = i & 127;
    float x = bf2f(row[4096 + i]);
    float x2, c, si;
    if (d < 64) { x2 = -bf2f(row[4096 + h*128 + d + 64]); c = cs[d];    si = sn[d]; }
    else        { x2 =  bf2f(row[4096 + h*128 + d - 64]); c = cs[d-64]; si = sn[d-64]; }
    K[((size_t)(b*KVH_ + h)*S_ + s)*HD_ + d] = f2bf(x*c + x2*si);
  }
}

// ---------------- GEMM v2: 256x256 tile, BK=64, 8-phase counted-vmcnt ----------------
// C[M][N] = A[M][K] * Bt[N][K]^T.  8 waves (2M x 4N), per-wave 128x64 output.
// LDS 128KB: 2 K-tile buffers x {A 32KB, B 32KB}, each operand 2 halves of 16KB.
// st_16x32 swizzle: subtile [16r][32k] (1024B), kbyte ^= ((r_in>>3)&1)<<5.
// Stage slots (1 half-tile/phase): ph1:A0(buf1,t+1) ph2:A1(buf1,t+1)
// ph3:B0(buf0,t+2) ph4:B1(buf0,t+2) ph5:A0(buf0,t+2) ph6:A1(buf0,t+2)
// ph7:B0(buf1,t+3) ph8:B1(buf1,t+3).  vmcnt(4) at ph4/ph8 only.

#define BAR() asm volatile("s_barrier" ::: "memory")
#define VMC4() asm volatile("s_waitcnt vmcnt(4)" ::: "memory")
#define SB0() __builtin_amdgcn_sched_barrier(0)

#define STAGE(buf, isB, h, kt) do {                                          \
  const unsigned short* _src = (isB) ? Bt : A;                               \
  size_t _rb = (size_t)(((isB) ? bn : bm)*256 + (h)*128);                    \
  _Pragma("unroll") for (int _rr = 0; _rr < 2; ++_rr) {                      \
    int _s = _rr*8 + wv;                                                     \
    gld_lds16(_src + (_rb + (size_t)((_s>>1)*16))*Kd                         \
                   + (size_t)((kt)*64 + (_s&1)*32) + lane_off,               \
              ldsc + (buf)*65536 + (isB)*32768 + (h)*16384 + _s*1024);       \
  }                                                                          \
} while (0)

#define LDA(dst, buf, mh) do {                                               \
  _Pragma("unroll") for (int _i = 0; _i < 4; ++_i)                           \
  _Pragma("unroll") for (int _kk = 0; _kk < 2; ++_kk)                        \
    dst[_i*2+_kk] = *(const s16x8*)(ldsc + (buf)*65536 + wr*16384            \
                    + ((((mh)*4+_i)*2+_kk)*1024) + aswz);                    \
} while (0)

#define LDB(dst, buf, nh) do {                                               \
  _Pragma("unroll") for (int _j = 0; _j < 2; ++_j)                           \
  _Pragma("unroll") for (int _kk = 0; _kk < 2; ++_kk)                        \
    dst[_j*2+_kk] = *(const s16x8*)(ldsc + (buf)*65536 + 32768               \
                    + (wc>>1)*16384                                          \
                    + ((((wc&1)*4+(nh)*2+_j)*2+_kk)*1024) + aswz);           \
} while (0)

#define MFMA_Q(Aa, Bb, MH, NH) do {                                          \
  __builtin_amdgcn_s_setprio(1);                                            \
  _Pragma("unroll") for (int _i = 0; _i < 4; ++_i)                           \
  _Pragma("unroll") for (int _j = 0; _j < 2; ++_j)                           \
  _Pragma("unroll") for (int _kk = 0; _kk < 2; ++_kk)                        \
    acc[(MH)*4+_i][(NH)*2+_j] = __builtin_amdgcn_mfma_f32_16x16x32_bf16(     \
        Aa[_i*2+_kk], Bb[_j*2+_kk], acc[(MH)*4+_i][(NH)*2+_j], 0, 0, 0);     \
  __builtin_amdgcn_s_setprio(0);                                            \
} while (0)

template<int OUTF32>
__global__ __launch_bounds__(512, 2)
void k_gemm8(const unsigned short* __restrict__ A, const unsigned short* __restrict__ Bt,
             void* __restrict__ C, int Kdim, int N, int MB) {
  __shared__ __align__(16) char ldsbuf[131072];
  char* ldsc = ldsbuf;
  const size_t Kd = (size_t)Kdim;
  const int NT = Kdim >> 6;

  // bijective XCD swizzle on flattened grid; bm fastest (B-panel L2 reuse)
  int nwg = gridDim.x;
  int flat = blockIdx.x;
  int q = nwg >> 3, r8 = nwg & 7, xcd = flat & 7, off = flat >> 3;
  int wg = (xcd < r8 ? xcd*(q+1) : r8*(q+1) + (xcd-r8)*q) + off;
  int bm = wg % MB, bn = wg / MB;

  int tid = threadIdx.x;
  int lane = tid & 63, wv = tid >> 6;
  int wr = wv >> 2, wc = wv & 3;          // 2M x 4N waves
  int l15 = lane & 15, l4 = lane >> 4;
  const int aswz = (l15 << 6) + ((l4 << 4) ^ ((l15 & 8) ? 32 : 0));
  const size_t lane_off = (size_t)(lane >> 2) * Kd
                        + (size_t)(((lane & 3) << 3) ^ ((lane & 32) >> 1));

  fx4 acc[8][4] = {};
  s16x8 Afr[8], B0fr[4], B1fr[4];

  // prologue: buf0 tile0 full, buf1 tile1 B-halves; then drain buf0
  STAGE(0, 0, 0, 0); STAGE(0, 0, 1, 0);
  STAGE(0, 1, 0, 0); STAGE(0, 1, 1, 0);
  STAGE(1, 1, 0, 1); STAGE(1, 1, 1, 1);
  VMC4();
  BAR();

  for (int t2 = 0; t2 < NT; t2 += 2) {
    int tb1 = t2 + 1;
    int tn0 = t2 + 2; if (tn0 >= NT) tn0 -= NT;
    int tn1 = t2 + 3; if (tn1 >= NT) tn1 -= NT;
    // ph1: Q(0,0) buf0
    LDA(Afr, 0, 0); LDB(B0fr, 0, 0);
    STAGE(1, 0, 0, tb1);
    BAR();
    MFMA_Q(Afr, B0fr, 0, 0);
    SB0(); BAR();
    // ph2: Q(0,1)
    LDB(B1fr, 0, 1);
    STAGE(1, 0, 1, tb1);
    BAR();
    MFMA_Q(Afr, B1fr, 0, 1);
    SB0(); BAR();
    // ph3: Q(1,1)
    LDA(Afr, 0, 1);
    STAGE(0, 1, 0, tn0);
    BAR();
    MFMA_Q(Afr, B1fr, 1, 1);
    SB0(); BAR();
    // ph4: Q(1,0)
    STAGE(0, 1, 1, tn0);
    BAR();
    MFMA_Q(Afr, B0fr, 1, 0);
    SB0(); VMC4(); BAR();
    // ph5: Q(0,0) buf1
    LDA(Afr, 1, 0); LDB(B0fr, 1, 0);
    STAGE(0, 0, 0, tn0);
    BAR();
    MFMA_Q(Afr, B0fr, 0, 0);
    SB0(); BAR();
    // ph6: Q(0,1)
    LDB(B1fr, 1, 1);
    STAGE(0, 0, 1, tn0);
    BAR();
    MFMA_Q(Afr, B1fr, 0, 1);
    SB0(); BAR();
    // ph7: Q(1,1)
    LDA(Afr, 1, 1);
    STAGE(1, 1, 0, tn1);
    BAR();
    MFMA_Q(Afr, B1fr, 1, 1);
    SB0(); BAR();
    // ph8: Q(1,0)
    STAGE(1, 1, 1, tn1);
    BAR();
    MFMA_Q(Afr, B0fr, 1, 0);
    SB0(); VMC4(); BAR();
  }

  // epilogue: C-write (m = frag*16 + l4*4 + r, n = frag*16 + l15)
  int m0 = bm*256 + wr*128 + l4*4;
  int n0 = bn*256 + wc*64 + l15;
#pragma unroll
  for (int mf = 0; mf < 8; ++mf)
#pragma unroll
    for (int nf = 0; nf < 4; ++nf)
#pragma unroll
      for (int r = 0; r < 4; ++r) {
        int m = m0 + mf*16 + r;
        int n = n0 + nf*16;
        float v = acc[mf][nf][r];
        if (OUTF32) ((float*)C)[(size_t)m*N + n] = v;
        else ((unsigned short*)C)[(size_t)m*N + n] = f2bf(v);
      }
}

// ---------------- attention (unchanged from R2) ----------------

__global__ __launch_bounds__(256)
void k_attn2(const unsigned short* __restrict__ Q, const unsigned short* __restrict__ K,
             const unsigned short* __restrict__ Vt, unsigned short* __restrict__ Aout) {
  __shared__ unsigned short k_lds[32*128];
  __shared__ unsigned short v_lds[128*32];
  const float C1 = 0.08838834764831845f * 2.0f * 1.4426950408889634f / 30.0f;
  const float C2 = 30.0f * 1.4426950408889634f;
  int tpair = blockIdx.x;
  int bh = blockIdx.y;
  int b = bh / H_, h = bh % H_;
  int kvh = h / GRP_;
  int tid = threadIdx.x, lane = tid & 63, wv = tid >> 6;
  int l15 = lane & 15, l4 = lane >> 4;
  const unsigned short* Qb = Q + (size_t)bh * S_ * HD_;
  const unsigned short* Kb = K + (size_t)(b*KVH_ + kvh) * S_ * HD_;
  const unsigned short* Vb = Vt + (size_t)(b*KVH_ + kvh) * HD_ * S_;

  for (int sp = 0; sp < 2; ++sp) {
    int strip = sp ? (15 - tpair) : tpair;
    int q0 = strip * 128;
    int qbase = q0 + wv * 32;
    s16x8 bq[2][4];
#pragma unroll
    for (int qf = 0; qf < 2; ++qf)
#pragma unroll
      for (int kb = 0; kb < 4; ++kb)
        bq[qf][kb] = *(const s16x8*)&Qb[(size_t)(qbase + qf*16 + l15)*HD_ + kb*32 + l4*8];
    fx4 oacc[2][8] = {};
    float sump[2] = {0.f, 0.f};
    int ntiles = q0/32 + 4;
    for (int t = 0; t < ntiles; ++t) {
      int kbase = t*32;
      for (int it = 0; it < 2; ++it) {
        int c = it*256 + tid;
        int kr = c >> 4;
        int kd = ((c & 15) ^ (kr & 7)) * 8;
        gld_lds16(&Kb[(size_t)(kbase + kr)*HD_ + kd], &k_lds[it*2048 + wv*512]);
        int vd = c >> 2;
        int vk = ((c & 3) ^ (vd & 3)) * 8;
        gld_lds16(&Vb[(size_t)vd*S_ + kbase + vk], &v_lds[it*2048 + wv*512]);
      }
      __syncthreads();
      if (kbase <= qbase + 31) {
        fx4 sst[2][2] = {};
#pragma unroll
        for (int nb = 0; nb < 2; ++nb)
#pragma unroll
          for (int kb = 0; kb < 4; ++kb) {
            s16x8 kf = *(const s16x8*)&k_lds[(nb*16 + l15)*128 + (((kb*4 + l4) ^ (l15 & 7)) * 8)];
            sst[nb][0] = __builtin_amdgcn_mfma_f32_16x16x32_bf16(kf, bq[0][kb], sst[nb][0], 0, 0, 0);
            sst[nb][1] = __builtin_amdgcn_mfma_f32_16x16x32_bf16(kf, bq[1][kb], sst[nb][1], 0, 0, 0);
          }
        s16x8 pf[2];
#pragma unroll
        for (int qf = 0; qf < 2; ++qf) {
          int qr = qbase + qf*16 + l15;
          uint32_t w[4];
          float psum = 0.f;
#pragma unroll
          for (int nb = 0; nb < 2; ++nb) {
            float pv[4];
#pragma unroll
            for (int r = 0; r < 4; ++r) {
              int kk = kbase + nb*16 + l4*4 + r;
              float sraw = sst[nb][qf][r];
              float e2 = __builtin_amdgcn_exp2f(-fabsf(sraw) * C1);
              float th = (1.f - e2) * __builtin_amdgcn_rcpf(1.f + e2);
              float th_s = __uint_as_float(__float_as_uint(th) |
                                           (__float_as_uint(sraw) & 0x80000000u));
              float p = __builtin_amdgcn_exp2f(th_s * C2 - C2);
              p = (kk <= qr) ? p : 0.f;
              psum += p;
              pv[r] = p;
            }
            w[nb*2]   = pk2(pv[0], pv[1]);
            w[nb*2+1] = pk2(pv[2], pv[3]);
          }
          sump[qf] += psum;
          uint32_t a0x = __shfl_xor((int)w[0], 16), a1x = __shfl_xor((int)w[1], 16);
          uint32_t b0x = __shfl_xor((int)w[2], 16), b1x = __shfl_xor((int)w[3], 16);
          bool up = (l4 & 1);
          uint32_t VA0 = up ? a0x : w[0], VA1 = up ? a1x : w[1];
          uint32_t VA2 = up ? w[0] : a0x, VA3 = up ? w[1] : a1x;
          uint32_t VB0 = up ? b0x : w[2], VB1 = up ? b1x : w[3];
          uint32_t VB2 = up ? w[2] : b0x, VB3 = up ? w[3] : b1x;
          bool lowh = (l4 < 2);
          uint32_t X0 = lowh ? VB0 : VA0, X1 = lowh ? VB1 : VA1;
          uint32_t X2 = lowh ? VB2 : VA2, X3 = lowh ? VB3 : VA3;
          uint32_t Y0 = __shfl_xor((int)X0, 32), Y1 = __shfl_xor((int)X1, 32);
          uint32_t Y2 = __shfl_xor((int)X2, 32), Y3 = __shfl_xor((int)X3, 32);
          union { uint32_t u[4]; s16x8 v; } tw;
          tw.u[0] = (l4 == 0) ? VA0 : (l4 == 3) ? VB0 : Y0;
          tw.u[1] = (l4 == 0) ? VA1 : (l4 == 3) ? VB1 : Y1;
          tw.u[2] = (l4 == 0) ? VA2 : (l4 == 3) ? VB2 : Y2;
          tw.u[3] = (l4 == 0) ? VA3 : (l4 == 3) ? VB3 : Y3;
          pf[qf] = tw.v;
        }
#pragma unroll
        for (int db = 0; db < 8; ++db) {
          int d = db*16 + l15;
          s16x8 vf = *(const s16x8*)&v_lds[d*32 + ((l4 ^ (d & 3)) * 8)];
          oacc[0][db] = __builtin_amdgcn_mfma_f32_16x16x32_bf16(vf, pf[0], oacc[0][db], 0, 0, 0);
          oacc[1][db] = __builtin_amdgcn_mfma_f32_16x16x32_bf16(vf, pf[1], oacc[1][db], 0, 0, 0);
        }
      }
      __syncthreads();
    }
#pragma unroll
    for (int qf = 0; qf < 2; ++qf) {
      float s = sump[qf];
      s += __shfl_xor(s, 16);
      s += __shfl_xor(s, 32);
      float rn = __builtin_amdgcn_rcpf(s);
      int q = qbase + qf*16 + l15;
#pragma unroll
      for (int db = 0; db < 8; ++db) {
        ushort4 o;
        o.x = f2bf(oacc[qf][db][0] * rn);
        o.y = f2bf(oacc[qf][db][1] * rn);
        o.z = f2bf(oacc[qf][db][2] * rn);
        o.w = f2bf(oacc[qf][db][3] * rn);
        *(ushort4*)&Aout[(size_t)(b*S_ + q)*4096 + h*HD_ + db*16 + l4*4] = o;
      }
    }
  }
}

// ---------------- launch ----------------

extern "C" void kernel_launch(void* const* d_in, const int* in_sizes, int n_in,
                              void* d_out, int out_size, void* d_ws, size_t ws_size,
                              hipStream_t stream) {
  (void)in_sizes; (void)n_in; (void)out_size; (void)ws_size;
  const float* hidden = (const float*)d_in[0];
  const float* q_w = (const float*)d_in[3];
  const float* k_w = (const float*)d_in[4];
  const float* v_w = (const float*)d_in[5];
  const float* o_w = (const float*)d_in[6];
  char* ws = (char*)d_ws;
  unsigned short* hidden_bf = (unsigned short*)(ws + 0);           // 32 MiB
  unsigned short* qkv_wt    = (unsigned short*)(ws + 33554432);    // 48 MiB
  unsigned short* o_wt      = (unsigned short*)(ws + 83886080);    // 32 MiB
  unsigned short* qkv       = (unsigned short*)(ws + 117440512);   // 48 MiB
  unsigned short* Qb        = (unsigned short*)(ws + 167772160);   // 32 MiB
  unsigned short* Kb        = (unsigned short*)(ws + 201326592);   // 8 MiB
  unsigned short* Vt        = (unsigned short*)(ws + 209715200);   // 8 MiB
  unsigned short* attn_out  = (unsigned short*)(ws + 218103808);   // 32 MiB

  dim3 tb(32, 8);
  k_f2bf<<<2048, 256, 0, stream>>>(hidden, hidden_bf, (B_*S_*D_)/4);
  k_transpose_w<<<dim3(128, 128), tb, 0, stream>>>(q_w, 4096, qkv_wt);
  k_transpose_w<<<dim3(128, 32),  tb, 0, stream>>>(k_w, 1024, qkv_wt + (size_t)4096*4096);
  k_transpose_w<<<dim3(128, 32),  tb, 0, stream>>>(v_w, 1024, qkv_wt + (size_t)5120*4096);
  k_transpose_w<<<dim3(128, 128), tb, 0, stream>>>(o_w, 4096, o_wt);
  k_gemm8<0><<<dim3(16*24), 512, 0, stream>>>(hidden_bf, qkv_wt, qkv, D_, NQKV, 16);
  k_rope<<<B_*S_, 256, 0, stream>>>(qkv, Qb, Kb);
  k_transpose_v<<<dim3(S_/32, HD_/32, B_*KVH_), tb, 0, stream>>>(qkv, Vt);
  k_attn2<<<dim3(8, B_*H_), 256, 0, stream>>>(Qb, Kb, Vt, attn_out);
  k_gemm8<1><<<dim3(16*16), 512, 0, stream>>>(attn_out, o_wt, d_out, D_, D_, 16);
}